// Round 5
// baseline (206.569 us; speedup 1.0000x reference)
//
#include <hip/hip_runtime.h>

#define NCOL 10752   // 512*21
#define NG 15
#define NT37 37
#define NT23 23
#define WS_NEED 913408   // 223 k-chunks * 4096 B of 64-row A images

typedef __bf16 bf16;
typedef __attribute__((ext_vector_type(8))) __bf16 bf16x8;
typedef __attribute__((ext_vector_type(4))) __bf16 bf16x4;
typedef __attribute__((ext_vector_type(4))) float f32x4;

__constant__ int c_gsize[NG]  = {64,128,256,96,160,224,192,288,320,112,80,48,32,16,32};
__constant__ int c_gstart[NG] = {0,64,192,448,544,704,928,1120,1408,1728,1840,1920,1968,2000,2016};

// ---- 64-row tiles (barrier-free kernel), largest groups first ----
__constant__ int t37_grp[NT37]  = {8,8,8,8,8, 7,7,7,7,7, 2,2,2,2, 5,5,5,5, 6,6,6, 4,4,4, 1,1, 9,9, 3,3, 10,10, 0, 11, 12, 14, 13};
__constant__ int t37_row[NT37]  = {0,64,128,192,256, 0,64,128,192,256, 0,64,128,192, 0,64,128,192, 0,64,128, 0,64,128, 0,64, 0,64, 0,64, 0,64, 0, 0, 0, 0, 0};
__constant__ int t37_kn[NT37]   = {10,10,10,10,10, 9,9,9,9,9, 8,8,8,8, 7,7,7,7, 6,6,6, 5,5,5, 4,4, 4,4, 3,3, 3,3, 2, 2, 1, 1, 1};
// prefix sum of t37_kn, units of 2048 bf16 (4 KB)
__constant__ int t37_base[NT37] = {0,10,20,30,40, 50,59,68,77,86, 95,103,111,119, 127,134,141,148, 155,161,167, 173,178,183, 188,192, 196,200, 204,207, 210,213, 216, 218, 220, 221, 222};

// ---- 128-row tiles (fallback kernel) ----
__constant__ int t23_grp[NT23] = {8,8,8,7,7,7,2,2,5,5,6,6,4,4,1,9,3,10,0,11,12,14,13};
__constant__ int t23_row[NT23] = {0,128,256,0,128,256,0,128,0,128,0,128,0,128,0,0,0,0,0,0,0,0,0};

struct MatPtrs { const float* p[NG]; };

constexpr int BKp = 40;   // padded k extent of LDS B buffers

__device__ __forceinline__ int bkey(int col) { return ((col >> 2) & 3) << 3; }

// ---------------------------------------------------------------------------
// Pre-pass: 64-row fragment-major bf16 tile images.
// k-chunk kt of tile t: subtile st (0..3), lane l: holds
// A[row0 + st*16 + (l&15)][kt*32 + (l>>4)*8 .. +7], zero-padded outside group.
// This is exactly the MFMA A-fragment order: one dwordx4 per lane per frag.
// ---------------------------------------------------------------------------
__global__ __launch_bounds__(256)
void prep_kernel(MatPtrs mats, bf16* __restrict__ ws)
{
    const int kt = blockIdx.x, tile = blockIdx.y;
    if (kt >= t37_kn[tile]) return;
    const int grp  = t37_grp[tile];
    const int row0 = t37_row[tile];
    const int g    = c_gsize[grp];
    const float* __restrict__ M = mats.p[grp];
    bf16* dst = ws + (size_t)(t37_base[tile] + kt) * 2048;

    const int u    = threadIdx.x;        // 0..255: st = u>>6, lane = u&63
    const int l    = u & 63;
    const int st   = u >> 6;
    const int row  = row0 + st * 16 + (l & 15);
    const int kcol = kt * 32 + (l >> 4) * 8;
    bf16x8 w = {};
    if (row < g && kcol < g) {           // g % 16 == 0 -> octet fully in/out
        const float* src = M + (size_t)row * g + kcol;
        #pragma unroll
        for (int j = 0; j < 8; j++) w[j] = (bf16)src[j];
    }
    *(bf16x8*)(dst + (size_t)u * 8) = w;
}

// ---------------------------------------------------------------------------
// Barrier-free main kernel. Each wave autonomously computes a 64-row x 32-col
// output slab: A-frags global->reg from the pre-tiled image (L1/L2-hot),
// X staged through a PRIVATE per-wave LDS buffer (dbuf, XOR-swizzled).
// No s_barrier anywhere: same-wave LDS write->read needs only lgkmcnt
// (compiler-inserted). Waves de-synchronize -> smooth HBM demand.
// regs ~90 -> launch_bounds(256,5): 5 waves/SIMD, 20 waves/CU; LDS 20.5 KB.
// ---------------------------------------------------------------------------
__global__ __launch_bounds__(256, 5)
void matapply_kernel(const float* __restrict__ x, const bf16* __restrict__ aws,
                     float* __restrict__ out)
{
    __shared__ bf16 sB[4][2][32 * BKp];  // [wave][dbuf][col*40 + k'] - private per wave

    const int tid    = threadIdx.x;
    const int colb   = blockIdx.x * 128;
    const int tileid = blockIdx.y;

    const int grp  = t37_grp[tileid];
    const int g    = c_gsize[grp];
    const int s    = c_gstart[grp];
    const int row0 = t37_row[tileid];
    const int nIter = t37_kn[tileid];
    const bf16* __restrict__ aimg = aws + (size_t)t37_base[tileid] * 2048;

    const int wave = tid >> 6;
    const int lane = tid & 63;
    const int wc   = wave * 32;          // wave's column slab
    const int lm   = lane & 15;
    const int kq   = lane >> 4;
    const int kb   = kq * 8;

    // X staging assignment: lane covers cols bC..bC+3 (f32x4) at k rows bK..bK+3
    const int bC = (lane & 7) * 4;       // 8 lanes x 4 cols = 32
    const int bK = (lane >> 3) * 4;      // 8 groups x 4 k   = 32

    const float* __restrict__ xbase = x + (size_t)(s + bK) * NCOL + colb + wc + bC;
    bf16* __restrict__ sBw0 = &sB[wave][0][0];
    bf16* __restrict__ sBw1 = &sB[wave][1][0];

    f32x4 acc[4][2];
    #pragma unroll
    for (int i = 0; i < 4; i++) {
        acc[i][0] = (f32x4){0.f, 0.f, 0.f, 0.f};
        acc[i][1] = (f32x4){0.f, 0.f, 0.f, 0.f};
    }

    // ---- prologue: issue X(0) ----
    float4 xv[4];
    #pragma unroll
    for (int q = 0; q < 4; q++)
        xv[q] = *(const float4*)(xbase + (size_t)q * NCOL);

    for (int it = 0; it < nIter; ++it) {
        bf16* __restrict__ sBw = (it & 1) ? sBw1 : sBw0;

        // ---- stage B(t) from xv (first use triggers the vmcnt wait;
        //      loads are ~1 iteration old in steady state) ----
        #pragma unroll
        for (int cc = 0; cc < 4; cc++) {
            const int col = bC + cc;
            bf16x4 w;
            w[0] = (bf16)xv[0][cc]; w[1] = (bf16)xv[1][cc];
            w[2] = (bf16)xv[2][cc]; w[3] = (bf16)xv[3][cc];
            *(bf16x4*)&sBw[col * BKp + (bK ^ bkey(col))] = w;
        }

        // ---- issue X(t+1): in flight across the whole compute phase ----
        if (it + 1 < nIter) {
            const size_t roff = (size_t)(it + 1) * 32;
            #pragma unroll
            for (int q = 0; q < 4; q++)
                xv[q] = *(const float4*)(xbase + (roff + q) * NCOL);
        }

        // ---- A-frags straight to registers (image is fragment-major) ----
        bf16x8 av[4];
        const bf16* ai = aimg + (size_t)it * 2048 + lane * 8;
        #pragma unroll
        for (int i = 0; i < 4; i++)
            av[i] = *(const bf16x8*)(ai + i * 512);

        // ---- read own B-frags (lgkmcnt ordering vs ds_writes above) ----
        bf16x8 bfr[2];
        #pragma unroll
        for (int j = 0; j < 2; j++) {
            const int col = j * 16 + lm;
            bfr[j] = *(const bf16x8*)&sBw[col * BKp + (kb ^ bkey(col))];
        }

        #pragma unroll
        for (int i = 0; i < 4; i++) {
            acc[i][0] = __builtin_amdgcn_mfma_f32_16x16x32_bf16(av[i], bfr[0], acc[i][0], 0, 0, 0);
            acc[i][1] = __builtin_amdgcn_mfma_f32_16x16x32_bf16(av[i], bfr[1], acc[i][1], 0, 0, 0);
        }
    }

    // ---- epilogue: C/D layout col=lane&15, row=(lane>>4)*4+reg ----
    #pragma unroll
    for (int i = 0; i < 4; i++) {
        #pragma unroll
        for (int r = 0; r < 4; r++) {
            const int row = row0 + i * 16 + kq * 4 + r;
            if (row < g) {
                float* orow = out + (size_t)(s + row) * NCOL + colb + wc;
                orow[lm]      = acc[i][0][r];
                orow[16 + lm] = acc[i][1][r];
            }
        }
    }
}

// ---------------------------------------------------------------------------
// Fallback (round-0 kernel, verbatim, 128-row tiles): used if ws too small.
// ---------------------------------------------------------------------------
__global__ __launch_bounds__(256)
void matapply_fb(const float* __restrict__ x, MatPtrs mats, float* __restrict__ out)
{
    __shared__ bf16 sAf[2][128][BKp];
    __shared__ bf16 sBf[2][128][BKp];

    const int tid    = threadIdx.x;
    const int colb   = blockIdx.x * 128;
    const int tileid = blockIdx.y;

    const int grp  = t23_grp[tileid];
    const int row0 = t23_row[tileid];
    const int g    = c_gsize[grp];
    const int s    = c_gstart[grp];
    const float* __restrict__ M = mats.p[grp];

    const int wave = tid >> 6;
    const int lane = tid & 63;
    const int wr   = (wave & 1) * 64;
    const int wc   = (wave >> 1) * 64;
    const int lm   = lane & 15;
    const int kq   = lane >> 4;
    const int kb   = kq * 8;

    const int aK = (tid & 7) * 4;
    const int aR = tid >> 3;
    const int bC = (tid & 31) * 4;
    const int bK = (tid >> 5) * 4;

    const int nIter = (g + 31) / 32;

    f32x4 acc[4][4];
    #pragma unroll
    for (int i = 0; i < 4; i++)
        #pragma unroll
        for (int j = 0; j < 4; j++)
            acc[i][j] = (f32x4){0.f, 0.f, 0.f, 0.f};

    float4 av[4], xv[4];

    #pragma unroll
    for (int i = 0; i < 4; i++) {
        int r = aR + 32 * i;
        av[i] = make_float4(0.f, 0.f, 0.f, 0.f);
        if ((row0 + r) < g && aK < g)
            av[i] = *(const float4*)(M + (size_t)(row0 + r) * g + aK);
    }
    #pragma unroll
    for (int j = 0; j < 4; j++)
        xv[j] = *(const float4*)(x + (size_t)(s + bK + j) * NCOL + colb + bC);

    #pragma unroll
    for (int i = 0; i < 4; i++) {
        int r = aR + 32 * i;
        bf16x4 w;
        w[0] = (bf16)av[i].x; w[1] = (bf16)av[i].y; w[2] = (bf16)av[i].z; w[3] = (bf16)av[i].w;
        *(bf16x4*)&sAf[0][r][aK] = w;
    }
    #pragma unroll
    for (int cc = 0; cc < 4; cc++) {
        int lc = bC + cc;
        bf16x4 w;
        #pragma unroll
        for (int j = 0; j < 4; j++)
            w[j] = (bf16)(((const float*)&xv[j])[cc]);
        *(bf16x4*)&sBf[0][lc][bK ^ (((lc >> 2) & 3) << 3)] = w;
    }
    __syncthreads();

    for (int it = 0; it < nIter; ++it) {
        const int cur = it & 1;
        const bool more = (it + 1) < nIter;

        if (more) {
            const int k0 = (it + 1) * 32;
            #pragma unroll
            for (int i = 0; i < 4; i++) {
                int r = aR + 32 * i;
                av[i] = make_float4(0.f, 0.f, 0.f, 0.f);
                if ((row0 + r) < g && (k0 + aK) < g)
                    av[i] = *(const float4*)(M + (size_t)(row0 + r) * g + k0 + aK);
            }
            #pragma unroll
            for (int j = 0; j < 4; j++)
                xv[j] = *(const float4*)(x + (size_t)(s + k0 + bK + j) * NCOL + colb + bC);
        }

        bf16x8 af[4], bfr[4];
        #pragma unroll
        for (int i = 0; i < 4; i++)
            af[i] = *(const bf16x8*)&sAf[cur][wr + i * 16 + lm][kb];
        #pragma unroll
        for (int j = 0; j < 4; j++) {
            int lc = wc + j * 16 + lm;
            bfr[j] = *(const bf16x8*)&sBf[cur][lc][kb ^ (((lc >> 2) & 3) << 3)];
        }
        #pragma unroll
        for (int i = 0; i < 4; i++)
            #pragma unroll
            for (int j = 0; j < 4; j++)
                acc[i][j] = __builtin_amdgcn_mfma_f32_16x16x32_bf16(af[i], bfr[j], acc[i][j], 0, 0, 0);

        if (more) {
            const int nxt = 1 - cur;
            #pragma unroll
            for (int i = 0; i < 4; i++) {
                int r = aR + 32 * i;
                bf16x4 w;
                w[0] = (bf16)av[i].x; w[1] = (bf16)av[i].y; w[2] = (bf16)av[i].z; w[3] = (bf16)av[i].w;
                *(bf16x4*)&sAf[nxt][r][aK] = w;
            }
            #pragma unroll
            for (int cc = 0; cc < 4; cc++) {
                int lc = bC + cc;
                bf16x4 w;
                #pragma unroll
                for (int j = 0; j < 4; j++)
                    w[j] = (bf16)(((const float*)&xv[j])[cc]);
                *(bf16x4*)&sBf[nxt][lc][bK ^ (((lc >> 2) & 3) << 3)] = w;
            }
            __syncthreads();
        }
    }

    #pragma unroll
    for (int i = 0; i < 4; i++) {
        #pragma unroll
        for (int r = 0; r < 4; r++) {
            int row = row0 + wr + i * 16 + kq * 4 + r;
            if (row < g) {
                float* orow = out + (size_t)(s + row) * NCOL + colb + wc;
                #pragma unroll
                for (int j = 0; j < 4; j++)
                    orow[j * 16 + lm] = acc[i][j][r];
            }
        }
    }
}

extern "C" void kernel_launch(void* const* d_in, const int* in_sizes, int n_in,
                              void* d_out, int out_size, void* d_ws, size_t ws_size,
                              hipStream_t stream)
{
    const float* x = (const float*)d_in[0];
    MatPtrs mp;
    for (int i = 0; i < NG; i++) mp.p[i] = (const float*)d_in[1 + i];
    float* out = (float*)d_out;

    if (d_ws != nullptr && ws_size >= (size_t)WS_NEED) {
        prep_kernel<<<dim3(10, NT37), dim3(256), 0, stream>>>(mp, (bf16*)d_ws);
        matapply_kernel<<<dim3(NCOL / 128, NT37), dim3(256), 0, stream>>>(
            x, (const bf16*)d_ws, out);
    } else {
        matapply_fb<<<dim3(NCOL / 128, NT23), dim3(256), 0, stream>>>(x, mp, out);
    }
}